// Round 8
// baseline (4209.242 us; speedup 1.0000x reference)
//
#include <hip/hip_runtime.h>
#include <cstdint>

#pragma STDC FP_CONTRACT OFF

// ---------------------------------------------------------------------------
// GridCLIP forward: hash-grid encode (16 levels x 8 dims) -> MLP 128->256->256->1024
// Output: label latent [N,512] flat, then image latent [N,512] flat.
// Round 8: gold = driver's XLA-compiled JAX reference. XLA's algebraic
// simplifier rewrites divide-by-constant into multiply-by-reciprocal:
// (x+10)/20 -> (x+10) * 0.05f  (reciprocal rounded f64->f32, rel bias 1.5e-8).
// That 1-ulp 'bounded' perturbation, amplified by scale=2^19 at L15, is the
// ~3.4e-6 error every clean chain produced. Replicate: t=rn(x+10);
// b=rn(t*0.05f); u=rn(b+1)*0.5; then f32 pos/frac/weights/accum (strict, no
// fma — XLA CPU/GPU does not contract elementwise HLOs). GEMMs stay fp32.
// ---------------------------------------------------------------------------

// ---------------- grid encode ----------------
__global__ __launch_bounds__(256) void grid_encode_kernel(
    const float* __restrict__ x, const float* __restrict__ emb,
    float* __restrict__ gh, int p0, int npts)
{
#pragma clang fp contract(off)
  int g = blockIdx.x * blockDim.x + threadIdx.x;
  if (g >= npts * 16) return;
  int pl = g >> 4;           // point within chunk
  int l  = g & 15;           // level
  int p  = p0 + pl;          // global point

  float x0 = x[3 * p + 0];
  float x1 = x[3 * p + 1];
  float x2 = x[3 * p + 2];

  // XLA chain: t = x+10 ; b = t * 0.05f (div->mul-reciprocal rewrite) ;
  // u = (b+1) * 0.5. Each op separately rounded f32; barriers stop hipcc
  // from contracting t*0.05f into the +1.
  float t0 = (x0 + 10.0f) * 0.05f;
  float t1 = (x1 + 10.0f) * 0.05f;
  float t2 = (x2 + 10.0f) * 0.05f;
  asm volatile("" : "+v"(t0), "+v"(t1), "+v"(t2));
  float u0 = (t0 + 1.0f) * 0.5f;
  float u1 = (t1 + 1.0f) * 0.5f;
  float u2 = (t2 + 1.0f) * 0.5f;
  asm volatile("" : "+v"(u0), "+v"(u1), "+v"(u2));

  float scale = (float)((16 << l) - 1);  // exact in fp32
  // (fma vs mul+add here is a proven identity: 0.5 is an exact ulp-multiple
  // of pos at every level — leave as plain ops)
  float pos0 = u0 * scale + 0.5f;
  float pos1 = u1 * scale + 0.5f;
  float pos2 = u2 * scale + 0.5f;

  float fb0 = floorf(pos0), fb1 = floorf(pos1), fb2 = floorf(pos2);
  float f0 = pos0 - fb0;  // exact
  float f1 = pos1 - fb1;
  float f2 = pos2 - fb2;
  uint32_t px = (uint32_t)fb0, py = (uint32_t)fb1, pz = (uint32_t)fb2;

  // all level sizes are powers of two -> modulo == AND
  uint32_t mask = (l < 3) ? ((4096u << (3 * l)) - 1u) : 2097151u;
  uint32_t off;
  if (l == 0)      off = 0u;
  else if (l == 1) off = 4096u;
  else if (l == 2) off = 36864u;
  else             off = 299008u + (uint32_t)(l - 3) * 2097152u;

  float wx[2] = {1.0f - f0, f0};
  float wy[2] = {1.0f - f1, f1};
  float wz[2] = {1.0f - f2, f2};

  float acc[8];
#pragma unroll
  for (int j = 0; j < 8; ++j) acc[j] = 0.0f;

#pragma unroll
  for (int c = 0; c < 8; ++c) {
    uint32_t cx = px + (uint32_t)(c & 1);
    uint32_t cy = py + (uint32_t)((c >> 1) & 1);
    uint32_t cz = pz + (uint32_t)((c >> 2) & 1);
    // w = (wx*wy)*wz in np.prod order; pure muls (not contractible)
    float w = wx[c & 1] * wy[(c >> 1) & 1] * wz[(c >> 2) & 1];
    uint32_t h = cx ^ (cy * 2654435761u) ^ (cz * 805459861u);
    uint32_t idx = (h & mask) + off;
    const float4* e = (const float4*)(emb + (size_t)idx * 8);
    float4 e0 = e[0];
    float4 e1 = e[1];
    // strict mul-then-add (two roundings, no fma)
    float m0 = w * e0.x, m1 = w * e0.y, m2 = w * e0.z, m3 = w * e0.w;
    float m4 = w * e1.x, m5 = w * e1.y, m6 = w * e1.z, m7 = w * e1.w;
    asm volatile("" : "+v"(m0), "+v"(m1), "+v"(m2), "+v"(m3),
                      "+v"(m4), "+v"(m5), "+v"(m6), "+v"(m7));
    acc[0] += m0; acc[1] += m1; acc[2] += m2; acc[3] += m3;
    acc[4] += m4; acc[5] += m5; acc[6] += m6; acc[7] += m7;
  }

  float* dst = gh + (size_t)pl * 128 + l * 8;
  float4 o0 = {acc[0], acc[1], acc[2], acc[3]};
  float4 o1 = {acc[4], acc[5], acc[6], acc[7]};
  *(float4*)(dst + 0) = o0;
  *(float4*)(dst + 4) = o1;
}

// ---------------- fp32 tiled GEMM ----------------
// C[M,N] = act(A[M,K] @ W[K,N] + bias).  BM=BN=128, BK=8, 256 thr, 8x8/thread.
// SPLIT=1: final layer, scatter cols [0,512) -> label block, [512,1024) -> image.
template <int K, int N, int ACT, int SPLIT>
__global__ __launch_bounds__(256) void gemm_kernel(
    const float* __restrict__ A, const float* __restrict__ W,
    const float* __restrict__ bias, float* __restrict__ Cout,
    int rowBase, int nTotal)
{
  constexpr int BM = 128, BN = 128, BK = 8;
  __shared__ float As[BK][BM + 4];
  __shared__ float Ws[BK][BN + 4];

  const int tid = threadIdx.x;
  const int bm = blockIdx.x * BM;
  const int bn = blockIdx.y * BN;
  const int tr = tid >> 4;
  const int tc = tid & 15;
  const int a_row = tid >> 1;
  const int a_k   = (tid & 1) * 4;
  const int w_row = tid >> 5;
  const int w_col = (tid & 31) * 4;

  float acc[8][8];
#pragma unroll
  for (int i = 0; i < 8; ++i)
#pragma unroll
    for (int j = 0; j < 8; ++j) acc[i][j] = 0.0f;

  for (int k0 = 0; k0 < K; k0 += BK) {
    float4 av = *(const float4*)(A + (size_t)(bm + a_row) * K + (k0 + a_k));
    float4 wv = *(const float4*)(W + (size_t)(k0 + w_row) * N + (bn + w_col));
    As[a_k + 0][a_row] = av.x;
    As[a_k + 1][a_row] = av.y;
    As[a_k + 2][a_row] = av.z;
    As[a_k + 3][a_row] = av.w;
    *(float4*)&Ws[w_row][w_col] = wv;
    __syncthreads();
#pragma unroll
    for (int k = 0; k < BK; ++k) {
      float4 a0 = *(const float4*)&As[k][tr * 8 + 0];
      float4 a1 = *(const float4*)&As[k][tr * 8 + 4];
      float4 w0 = *(const float4*)&Ws[k][tc * 8 + 0];
      float4 w1 = *(const float4*)&Ws[k][tc * 8 + 4];
      float ar[8] = {a0.x, a0.y, a0.z, a0.w, a1.x, a1.y, a1.z, a1.w};
      float wr[8] = {w0.x, w0.y, w0.z, w0.w, w1.x, w1.y, w1.z, w1.w};
#pragma unroll
      for (int i = 0; i < 8; ++i)
#pragma unroll
        for (int j = 0; j < 8; ++j) acc[i][j] += ar[i] * wr[j];
    }
    __syncthreads();
  }

#pragma unroll
  for (int i = 0; i < 8; ++i) {
    int m = bm + tr * 8 + i;
#pragma unroll
    for (int j4 = 0; j4 < 8; j4 += 4) {
      int n = bn + tc * 8 + j4;
      float4 bv = *(const float4*)(bias + n);
      float4 v;
      v.x = acc[i][j4 + 0] + bv.x;
      v.y = acc[i][j4 + 1] + bv.y;
      v.z = acc[i][j4 + 2] + bv.z;
      v.w = acc[i][j4 + 3] + bv.w;
      if (ACT) {
        v.x = fmaxf(v.x, 0.0f);
        v.y = fmaxf(v.y, 0.0f);
        v.z = fmaxf(v.z, 0.0f);
        v.w = fmaxf(v.w, 0.0f);
      }
      if (SPLIT) {
        size_t row = (size_t)(rowBase + m);
        float* dst = (n < 512)
                         ? (Cout + row * 512 + n)
                         : (Cout + (size_t)nTotal * 512 + row * 512 + (n - 512));
        *(float4*)dst = v;
      } else {
        *(float4*)(Cout + (size_t)m * N + n) = v;
      }
    }
  }
}

// ---------------- launch ----------------
extern "C" void kernel_launch(void* const* d_in, const int* in_sizes, int n_in,
                              void* d_out, int out_size, void* d_ws, size_t ws_size,
                              hipStream_t stream)
{
  const float* x   = (const float*)d_in[0];
  const float* emb = (const float*)d_in[1];
  const float* W1  = (const float*)d_in[2];
  const float* b1  = (const float*)d_in[3];
  const float* W2  = (const float*)d_in[4];
  const float* b2  = (const float*)d_in[5];
  const float* W3  = (const float*)d_in[6];
  const float* b3  = (const float*)d_in[7];
  float* out = (float*)d_out;

  const int NPTS = in_sizes[0] / 3;  // 262144

  // chunk rows to fit workspace: gh[C,128] + h1[C,256] + h2[C,256] (f32)
  const size_t perRow = (size_t)(128 + 256 + 256) * sizeof(float);
  long long cmax = (long long)(ws_size / perRow);
  int C = (int)((cmax / 128) * 128);
  if (C > NPTS) C = NPTS;
  if (C < 128) C = 128;

  float* gh = (float*)d_ws;
  float* h1 = gh + (size_t)C * 128;
  float* h2 = h1 + (size_t)C * 256;

  for (int p0 = 0; p0 < NPTS; p0 += C) {
    int cur = (NPTS - p0 < C) ? (NPTS - p0) : C;

    int nthr = cur * 16;
    grid_encode_kernel<<<(nthr + 255) / 256, 256, 0, stream>>>(x, emb, gh, p0, cur);

    dim3 g1(cur / 128, 256 / 128);
    gemm_kernel<128, 256, 1, 0><<<g1, 256, 0, stream>>>(gh, W1, b1, h1, p0, NPTS);

    dim3 g2(cur / 128, 256 / 128);
    gemm_kernel<256, 256, 1, 0><<<g2, 256, 0, stream>>>(h1, W2, b2, h2, p0, NPTS);

    dim3 g3(cur / 128, 1024 / 128);
    gemm_kernel<256, 1024, 0, 1><<<g3, 256, 0, stream>>>(h2, W3, b3, out, p0, NPTS);
  }
}

// Round 9
// 1170.857 us; speedup vs baseline: 3.5950x; 3.5950x over previous
//
#include <hip/hip_runtime.h>
#include <cstdint>

#pragma STDC FP_CONTRACT OFF

// ---------------------------------------------------------------------------
// GridCLIP forward: hash-grid encode (16 levels x 8) -> MLP 128->256->256->1024
// Round 9: MLP moved to f16 MFMA (mfma_f32_16x16x32_f16). Activations kept
// scaled by 4096 in f16 (values ~1e-5..1e-4 would be fp16-subnormal; relu
// commutes with positive scale). Weights pre-converted per call to f16,
// TRANSPOSED (Wt[N][K]) so A- and B-tiles both stage coalesced and fragments
// read as contiguous ds_read_b128. Encode math identical to the R8 pass
// (XLA div->mul-by-reciprocal chain), output now scaled f16.
// ---------------------------------------------------------------------------

typedef _Float16 f16;
typedef __attribute__((ext_vector_type(8))) _Float16 f16x8;
typedef __attribute__((ext_vector_type(4))) float f32x4;

#define ACT_SCALE 4096.0f
#define INV_ACT_SCALE (1.0f / 4096.0f)

// ---------------- grid encode (bit-exact XLA chain, f16-scaled output) -----
__global__ __launch_bounds__(256) void grid_encode_kernel(
    const float* __restrict__ x, const float* __restrict__ emb,
    f16* __restrict__ gh, int p0, int npts)
{
#pragma clang fp contract(off)
  int g = blockIdx.x * blockDim.x + threadIdx.x;
  if (g >= npts * 16) return;
  int pl = g >> 4;           // point within chunk
  int l  = g & 15;           // level
  int p  = p0 + pl;          // global point

  float x0 = x[3 * p + 0];
  float x1 = x[3 * p + 1];
  float x2 = x[3 * p + 2];

  // XLA chain: t = (x+10) * 0.05f (div->mul-reciprocal) ; u = (t+1) * 0.5
  float t0 = (x0 + 10.0f) * 0.05f;
  float t1 = (x1 + 10.0f) * 0.05f;
  float t2 = (x2 + 10.0f) * 0.05f;
  asm volatile("" : "+v"(t0), "+v"(t1), "+v"(t2));
  float u0 = (t0 + 1.0f) * 0.5f;
  float u1 = (t1 + 1.0f) * 0.5f;
  float u2 = (t2 + 1.0f) * 0.5f;
  asm volatile("" : "+v"(u0), "+v"(u1), "+v"(u2));

  float scale = (float)((16 << l) - 1);
  float pos0 = u0 * scale + 0.5f;
  float pos1 = u1 * scale + 0.5f;
  float pos2 = u2 * scale + 0.5f;

  float fb0 = floorf(pos0), fb1 = floorf(pos1), fb2 = floorf(pos2);
  float f0 = pos0 - fb0;
  float f1 = pos1 - fb1;
  float f2 = pos2 - fb2;
  uint32_t px = (uint32_t)fb0, py = (uint32_t)fb1, pz = (uint32_t)fb2;

  uint32_t mask = (l < 3) ? ((4096u << (3 * l)) - 1u) : 2097151u;
  uint32_t off;
  if (l == 0)      off = 0u;
  else if (l == 1) off = 4096u;
  else if (l == 2) off = 36864u;
  else             off = 299008u + (uint32_t)(l - 3) * 2097152u;

  float wx[2] = {1.0f - f0, f0};
  float wy[2] = {1.0f - f1, f1};
  float wz[2] = {1.0f - f2, f2};

  float acc[8];
#pragma unroll
  for (int j = 0; j < 8; ++j) acc[j] = 0.0f;

#pragma unroll
  for (int c = 0; c < 8; ++c) {
    uint32_t cx = px + (uint32_t)(c & 1);
    uint32_t cy = py + (uint32_t)((c >> 1) & 1);
    uint32_t cz = pz + (uint32_t)((c >> 2) & 1);
    float w = wx[c & 1] * wy[(c >> 1) & 1] * wz[(c >> 2) & 1];
    uint32_t h = cx ^ (cy * 2654435761u) ^ (cz * 805459861u);
    uint32_t idx = (h & mask) + off;
    const float4* e = (const float4*)(emb + (size_t)idx * 8);
    float4 e0 = e[0];
    float4 e1 = e[1];
    float m0 = w * e0.x, m1 = w * e0.y, m2 = w * e0.z, m3 = w * e0.w;
    float m4 = w * e1.x, m5 = w * e1.y, m6 = w * e1.z, m7 = w * e1.w;
    asm volatile("" : "+v"(m0), "+v"(m1), "+v"(m2), "+v"(m3),
                      "+v"(m4), "+v"(m5), "+v"(m6), "+v"(m7));
    acc[0] += m0; acc[1] += m1; acc[2] += m2; acc[3] += m3;
    acc[4] += m4; acc[5] += m5; acc[6] += m6; acc[7] += m7;
  }

  // scaled f16 output (16B store)
  f16x8 o;
#pragma unroll
  for (int j = 0; j < 8; ++j) o[j] = (f16)(acc[j] * ACT_SCALE);
  *(f16x8*)&gh[(size_t)pl * 128 + l * 8] = o;
}

// ---------------- weight prep: f32 [K][N] -> f16 [N][K] --------------------
template <int K, int N>
__global__ __launch_bounds__(256) void prep_w(
    const float* __restrict__ W, f16* __restrict__ Wt)
{
  int i = blockIdx.x * 256 + threadIdx.x;  // i = n*K + k
  if (i >= N * K) return;
  int n = i / K, k = i - n * K;
  Wt[i] = (f16)W[(size_t)k * N + n];
}

// ---------------- f16 MFMA GEMM -------------------------------------------
// C[M,N] = act(A[M,K] @ Wt[N,K]^T + bias). BM=BN=128, BK=32, 4 waves (2x2),
// each wave 64x64 via 4x4 16x16x32 fragments.
// ACT=1: out f16 scaled (relu(acc + bias*S)). SPLIT=1: out f32, acc/S + bias,
// cols [0,512) -> label block, [512,1024) -> image block.
template <int K, int N, int ACT, int SPLIT>
__global__ __launch_bounds__(256) void mfma_gemm(
    const f16* __restrict__ A, const f16* __restrict__ Wt,
    const float* __restrict__ bias, void* __restrict__ Cout,
    int rowBase, int nTotal)
{
  constexpr int BM = 128, BN = 128, BK = 32, PK = BK + 8;  // padded k-stride
  __shared__ f16 As[BM * PK];
  __shared__ f16 Bs[BN * PK];

  const int tid  = threadIdx.x;
  const int lane = tid & 63;
  const int wid  = tid >> 6;     // 0..3
  const int wr   = wid >> 1;     // wave row 0..1
  const int wc   = wid & 1;      // wave col 0..1
  const int bm   = blockIdx.x * BM;
  const int bn   = blockIdx.y * BN;

  const int lr = lane & 15;          // fragment row (A) / col (B) / col (C)
  const int lk = (lane >> 4) * 8;    // k offset within fragment

  f32x4 acc[4][4];
#pragma unroll
  for (int i = 0; i < 4; ++i)
#pragma unroll
    for (int j = 0; j < 4; ++j) acc[i][j] = (f32x4){0.f, 0.f, 0.f, 0.f};

  for (int k0 = 0; k0 < K; k0 += BK) {
    // stage: 512 16B-chunks each for A and B; 2 chunks/thread each
#pragma unroll
    for (int s = 0; s < 2; ++s) {
      int c   = tid + s * 256;
      int row = c >> 2;
      int ko  = (c & 3) * 8;
      *(f16x8*)&As[row * PK + ko] =
          *(const f16x8*)&A[(size_t)(bm + row) * K + k0 + ko];
      *(f16x8*)&Bs[row * PK + ko] =
          *(const f16x8*)&Wt[(size_t)(bn + row) * K + k0 + ko];
    }
    __syncthreads();

    f16x8 af[4], bf[4];
#pragma unroll
    for (int i = 0; i < 4; ++i) {
      af[i] = *(const f16x8*)&As[(wr * 64 + i * 16 + lr) * PK + lk];
      bf[i] = *(const f16x8*)&Bs[(wc * 64 + i * 16 + lr) * PK + lk];
    }
#pragma unroll
    for (int i = 0; i < 4; ++i)
#pragma unroll
      for (int j = 0; j < 4; ++j)
        acc[i][j] = __builtin_amdgcn_mfma_f32_16x16x32_f16(
            af[i], bf[j], acc[i][j], 0, 0, 0);
    __syncthreads();
  }

  // epilogue: C/D frag mapping row=(lane>>4)*4+q, col=lane&15
  const int orow0 = bm + wr * 64;
  const int ocol0 = bn + wc * 64;
#pragma unroll
  for (int i = 0; i < 4; ++i) {
#pragma unroll
    for (int j = 0; j < 4; ++j) {
      int col = ocol0 + j * 16 + lr;
      float bv = bias[col];
#pragma unroll
      for (int q = 0; q < 4; ++q) {
        int row = orow0 + i * 16 + (lane >> 4) * 4 + q;
        float v = acc[i][j][q];
        if (ACT) {
          v = fmaxf(v + bv * ACT_SCALE, 0.0f);
          ((f16*)Cout)[(size_t)row * N + col] = (f16)v;
        } else {
          v = v * INV_ACT_SCALE + bv;
          size_t grow = (size_t)(rowBase + row);
          float* dst = (col < 512)
                           ? ((float*)Cout + grow * 512 + col)
                           : ((float*)Cout + (size_t)nTotal * 512 + grow * 512 +
                              (col - 512));
          *dst = v;
        }
      }
    }
  }
}

// ---------------- launch ----------------
extern "C" void kernel_launch(void* const* d_in, const int* in_sizes, int n_in,
                              void* d_out, int out_size, void* d_ws, size_t ws_size,
                              hipStream_t stream)
{
  const float* x   = (const float*)d_in[0];
  const float* emb = (const float*)d_in[1];
  const float* W1  = (const float*)d_in[2];
  const float* b1  = (const float*)d_in[3];
  const float* W2  = (const float*)d_in[4];
  const float* b2  = (const float*)d_in[5];
  const float* W3  = (const float*)d_in[6];
  const float* b3  = (const float*)d_in[7];
  float* out = (float*)d_out;

  const int NPTS = in_sizes[0] / 3;  // 262144

  // ws layout: Wt1 | Wt2 | Wt3 | gh(f16) | h1(f16) | h2(f16)
  f16* Wt1 = (f16*)d_ws;                 // 128*256
  f16* Wt2 = Wt1 + 128 * 256;            // 256*256
  f16* Wt3 = Wt2 + 256 * 256;            // 256*1024
  f16* wsAct = Wt3 + 256 * 1024;
  const size_t wtBytes = (size_t)(128 * 256 + 256 * 256 + 256 * 1024) * sizeof(f16);

  // chunk rows: gh C*128 f16 + h1 C*256 f16 + h2 C*256 f16 = 1280 B/row
  long long cmax = (long long)((ws_size - wtBytes) / 1280);
  int C = (int)((cmax / 128) * 128);
  if (C > NPTS) C = NPTS;
  if (C < 128) C = 128;

  f16* gh = wsAct;
  f16* h1 = gh + (size_t)C * 128;
  f16* h2 = h1 + (size_t)C * 256;

  // weight conversion (every call; deterministic)
  prep_w<128, 256><<<(128 * 256 + 255) / 256, 256, 0, stream>>>(W1, Wt1);
  prep_w<256, 256><<<(256 * 256 + 255) / 256, 256, 0, stream>>>(W2, Wt2);
  prep_w<256, 1024><<<(256 * 1024 + 255) / 256, 256, 0, stream>>>(W3, Wt3);

  for (int p0 = 0; p0 < NPTS; p0 += C) {
    int cur = (NPTS - p0 < C) ? (NPTS - p0) : C;

    int nthr = cur * 16;
    grid_encode_kernel<<<(nthr + 255) / 256, 256, 0, stream>>>(x, emb, gh, p0, cur);

    dim3 g1(cur / 128, 2);
    mfma_gemm<128, 256, 1, 0><<<g1, 256, 0, stream>>>(gh, Wt1, b1, h1, p0, NPTS);

    dim3 g2(cur / 128, 2);
    mfma_gemm<256, 256, 1, 0><<<g2, 256, 0, stream>>>(h1, Wt2, b2, h2, p0, NPTS);

    dim3 g3(cur / 128, 8);
    mfma_gemm<256, 1024, 0, 1><<<g3, 256, 0, stream>>>(h2, Wt3, b3, out, p0, NPTS);
  }
}

// Round 10
// 1108.551 us; speedup vs baseline: 3.7971x; 1.0562x over previous
//
#include <hip/hip_runtime.h>
#include <cstdint>

#pragma STDC FP_CONTRACT OFF

// ---------------------------------------------------------------------------
// GridCLIP forward: hash-grid encode (16 levels x 8) -> MLP 128->256->256->1024
// Round 10: GEMM restructured to the m97-proven shape: BK=64,
// global_load_lds(16B) staging into LINEAR LDS, XOR granule swizzle applied
// BOTH-sides (inverse-swizzled global source + swizzled ds_read; rule 21) to
// kill the 16-way bank conflict of 128B rows. Encode + epilogue identical to
// the R8/R9 passing math (XLA div->mul-reciprocal chain; scaled-f16 MLP).
// ---------------------------------------------------------------------------

typedef _Float16 f16;
typedef __attribute__((ext_vector_type(8))) _Float16 f16x8;
typedef __attribute__((ext_vector_type(4))) float f32x4;

#define ACT_SCALE 4096.0f
#define INV_ACT_SCALE (1.0f / 4096.0f)

// global(AS1) -> LDS(AS3) direct 16B load (CK-style address-space casts)
__device__ __forceinline__ void gld16(const void* g, void* l) {
  __builtin_amdgcn_global_load_lds(
      (const __attribute__((address_space(1))) void*)(uintptr_t)g,
      (__attribute__((address_space(3))) void*)(uint32_t)(uintptr_t)l,
      16, 0, 0);
}

// ---------------- grid encode (bit-exact XLA chain, f16-scaled output) -----
__global__ __launch_bounds__(256) void grid_encode_kernel(
    const float* __restrict__ x, const float* __restrict__ emb,
    f16* __restrict__ gh, int p0, int npts)
{
#pragma clang fp contract(off)
  int g = blockIdx.x * blockDim.x + threadIdx.x;
  if (g >= npts * 16) return;
  int pl = g >> 4;           // point within chunk
  int l  = g & 15;           // level
  int p  = p0 + pl;          // global point

  float x0 = x[3 * p + 0];
  float x1 = x[3 * p + 1];
  float x2 = x[3 * p + 2];

  // XLA chain: t = (x+10) * 0.05f (div->mul-reciprocal) ; u = (t+1) * 0.5
  float t0 = (x0 + 10.0f) * 0.05f;
  float t1 = (x1 + 10.0f) * 0.05f;
  float t2 = (x2 + 10.0f) * 0.05f;
  asm volatile("" : "+v"(t0), "+v"(t1), "+v"(t2));
  float u0 = (t0 + 1.0f) * 0.5f;
  float u1 = (t1 + 1.0f) * 0.5f;
  float u2 = (t2 + 1.0f) * 0.5f;
  asm volatile("" : "+v"(u0), "+v"(u1), "+v"(u2));

  float scale = (float)((16 << l) - 1);
  float pos0 = u0 * scale + 0.5f;
  float pos1 = u1 * scale + 0.5f;
  float pos2 = u2 * scale + 0.5f;

  float fb0 = floorf(pos0), fb1 = floorf(pos1), fb2 = floorf(pos2);
  float f0 = pos0 - fb0;
  float f1 = pos1 - fb1;
  float f2 = pos2 - fb2;
  uint32_t px = (uint32_t)fb0, py = (uint32_t)fb1, pz = (uint32_t)fb2;

  uint32_t mask = (l < 3) ? ((4096u << (3 * l)) - 1u) : 2097151u;
  uint32_t off;
  if (l == 0)      off = 0u;
  else if (l == 1) off = 4096u;
  else if (l == 2) off = 36864u;
  else             off = 299008u + (uint32_t)(l - 3) * 2097152u;

  float wx[2] = {1.0f - f0, f0};
  float wy[2] = {1.0f - f1, f1};
  float wz[2] = {1.0f - f2, f2};

  float acc[8];
#pragma unroll
  for (int j = 0; j < 8; ++j) acc[j] = 0.0f;

#pragma unroll
  for (int c = 0; c < 8; ++c) {
    uint32_t cx = px + (uint32_t)(c & 1);
    uint32_t cy = py + (uint32_t)((c >> 1) & 1);
    uint32_t cz = pz + (uint32_t)((c >> 2) & 1);
    float w = wx[c & 1] * wy[(c >> 1) & 1] * wz[(c >> 2) & 1];
    uint32_t h = cx ^ (cy * 2654435761u) ^ (cz * 805459861u);
    uint32_t idx = (h & mask) + off;
    const float4* e = (const float4*)(emb + (size_t)idx * 8);
    float4 e0 = e[0];
    float4 e1 = e[1];
    float m0 = w * e0.x, m1 = w * e0.y, m2 = w * e0.z, m3 = w * e0.w;
    float m4 = w * e1.x, m5 = w * e1.y, m6 = w * e1.z, m7 = w * e1.w;
    asm volatile("" : "+v"(m0), "+v"(m1), "+v"(m2), "+v"(m3),
                      "+v"(m4), "+v"(m5), "+v"(m6), "+v"(m7));
    acc[0] += m0; acc[1] += m1; acc[2] += m2; acc[3] += m3;
    acc[4] += m4; acc[5] += m5; acc[6] += m6; acc[7] += m7;
  }

  f16x8 o;
#pragma unroll
  for (int j = 0; j < 8; ++j) o[j] = (f16)(acc[j] * ACT_SCALE);
  *(f16x8*)&gh[(size_t)pl * 128 + l * 8] = o;
}

// ---------------- weight prep: f32 [K][N] -> f16 [N][K] --------------------
template <int K, int N>
__global__ __launch_bounds__(256) void prep_w(
    const float* __restrict__ W, f16* __restrict__ Wt)
{
  int i = blockIdx.x * 256 + threadIdx.x;  // i = n*K + k
  if (i >= N * K) return;
  int n = i / K, k = i - n * K;
  Wt[i] = (f16)W[(size_t)k * N + n];
}

// ---------------- f16 MFMA GEMM (m97 structure) ----------------------------
// C[M,N] = act(A[M,K] @ Wt[N,K]^T + bias). BM=BN=128, BK=64, 4 waves (2x2),
// wave tile 64x64 = 4x4 frags of 16x16x32. global_load_lds staging, linear
// LDS, granule swizzle g^=(row&7) on source+read (rule 21 both-sides).
// ACT=1: f16 scaled relu out. SPLIT=1: f32 out, cols [0,512)->label block,
// [512,1024)->image block.
template <int K, int N, int ACT, int SPLIT>
__global__ __launch_bounds__(256) void mfma_gemm(
    const f16* __restrict__ A, const f16* __restrict__ Wt,
    const float* __restrict__ bias, void* __restrict__ Cout,
    int rowBase, int nTotal)
{
  constexpr int BM = 128, BK = 64;
  __shared__ alignas(16) f16 As[BM * BK];
  __shared__ alignas(16) f16 Bs[BM * BK];

  const int tid  = threadIdx.x;
  const int lane = tid & 63;
  const int wid  = tid >> 6;     // 0..3
  const int wr   = wid >> 1;     // wave row 0..1
  const int wc   = wid & 1;      // wave col 0..1
  const int bm   = blockIdx.x * BM;
  const int bn   = blockIdx.y * BM;

  const int lr  = lane & 15;         // fragment row (A) / col (B/C)
  const int lkg = lane >> 4;         // k-granule within fragment (0..3)

  f32x4 acc[4][4];
#pragma unroll
  for (int i = 0; i < 4; ++i)
#pragma unroll
    for (int j = 0; j < 4; ++j) acc[i][j] = (f32x4){0.f, 0.f, 0.f, 0.f};

  // staging geometry (per wave, per instruction i: 8 rows x 64 f16)
  const int srow_off = lane >> 3;          // row within 8-row group
  const int sg       = lane & 7;           // dest granule

  for (int k0 = 0; k0 < K; k0 += BK) {
#pragma unroll
    for (int i = 0; i < 4; ++i) {
      const int r0  = wid * 32 + i * 8;
      const int row = r0 + srow_off;
      const int gs  = sg ^ (row & 7);      // inverse-swizzled source granule
      gld16(&A[(size_t)(bm + row) * K + k0 + gs * 8], &As[r0 * BK]);
      gld16(&Wt[(size_t)(bn + row) * K + k0 + gs * 8], &Bs[r0 * BK]);
    }
    __syncthreads();  // drains vmcnt (global_load_lds) + barrier

#pragma unroll
    for (int kk = 0; kk < 2; ++kk) {
      f16x8 af[4], bf[4];
#pragma unroll
      for (int i = 0; i < 4; ++i) {
        const int ar = wr * 64 + i * 16 + lr;
        const int br = wc * 64 + i * 16 + lr;
        af[i] = *(const f16x8*)&As[ar * BK + ((kk * 4 + lkg) ^ (ar & 7)) * 8];
        bf[i] = *(const f16x8*)&Bs[br * BK + ((kk * 4 + lkg) ^ (br & 7)) * 8];
      }
#pragma unroll
      for (int i = 0; i < 4; ++i)
#pragma unroll
        for (int j = 0; j < 4; ++j)
          acc[i][j] = __builtin_amdgcn_mfma_f32_16x16x32_f16(
              af[i], bf[j], acc[i][j], 0, 0, 0);
    }
    __syncthreads();
  }

  // epilogue: C/D frag mapping col=lane&15, row=(lane>>4)*4+q (m89-verified)
  const int orow0 = bm + wr * 64;
  const int ocol0 = bn + wc * 64;
#pragma unroll
  for (int i = 0; i < 4; ++i) {
#pragma unroll
    for (int j = 0; j < 4; ++j) {
      int col = ocol0 + j * 16 + lr;
      float bv = bias[col];
#pragma unroll
      for (int q = 0; q < 4; ++q) {
        int row = orow0 + i * 16 + (lane >> 4) * 4 + q;
        float v = acc[i][j][q];
        if (ACT) {
          v = fmaxf(v + bv * ACT_SCALE, 0.0f);
          ((f16*)Cout)[(size_t)row * N + col] = (f16)v;
        } else {
          v = v * INV_ACT_SCALE + bv;
          size_t grow = (size_t)(rowBase + row);
          float* dst = (col < 512)
                           ? ((float*)Cout + grow * 512 + col)
                           : ((float*)Cout + (size_t)nTotal * 512 + grow * 512 +
                              (col - 512));
          *dst = v;
        }
      }
    }
  }
}

// ---------------- launch ----------------
extern "C" void kernel_launch(void* const* d_in, const int* in_sizes, int n_in,
                              void* d_out, int out_size, void* d_ws, size_t ws_size,
                              hipStream_t stream)
{
  const float* x   = (const float*)d_in[0];
  const float* emb = (const float*)d_in[1];
  const float* W1  = (const float*)d_in[2];
  const float* b1  = (const float*)d_in[3];
  const float* W2  = (const float*)d_in[4];
  const float* b2  = (const float*)d_in[5];
  const float* W3  = (const float*)d_in[6];
  const float* b3  = (const float*)d_in[7];
  float* out = (float*)d_out;

  const int NPTS = in_sizes[0] / 3;  // 262144

  // ws layout: Wt1 | Wt2 | Wt3 | gh(f16) | h1(f16) | h2(f16)
  f16* Wt1 = (f16*)d_ws;                 // 128*256
  f16* Wt2 = Wt1 + 128 * 256;            // 256*256
  f16* Wt3 = Wt2 + 256 * 256;            // 256*1024
  f16* wsAct = Wt3 + 256 * 1024;
  const size_t wtBytes = (size_t)(128 * 256 + 256 * 256 + 256 * 1024) * sizeof(f16);

  // chunk rows: gh C*128 f16 + h1 C*256 f16 + h2 C*256 f16 = 1280 B/row
  long long cmax = (long long)((ws_size - wtBytes) / 1280);
  int C = (int)((cmax / 128) * 128);
  if (C > NPTS) C = NPTS;
  if (C < 128) C = 128;

  f16* gh = wsAct;
  f16* h1 = gh + (size_t)C * 128;
  f16* h2 = h1 + (size_t)C * 256;

  prep_w<128, 256><<<(128 * 256 + 255) / 256, 256, 0, stream>>>(W1, Wt1);
  prep_w<256, 256><<<(256 * 256 + 255) / 256, 256, 0, stream>>>(W2, Wt2);
  prep_w<256, 1024><<<(256 * 1024 + 255) / 256, 256, 0, stream>>>(W3, Wt3);

  for (int p0 = 0; p0 < NPTS; p0 += C) {
    int cur = (NPTS - p0 < C) ? (NPTS - p0) : C;

    int nthr = cur * 16;
    grid_encode_kernel<<<(nthr + 255) / 256, 256, 0, stream>>>(x, emb, gh, p0, cur);

    dim3 g1(cur / 128, 2);
    mfma_gemm<128, 256, 1, 0><<<g1, 256, 0, stream>>>(gh, Wt1, b1, h1, p0, NPTS);

    dim3 g2(cur / 128, 2);
    mfma_gemm<256, 256, 1, 0><<<g2, 256, 0, stream>>>(h1, Wt2, b2, h2, p0, NPTS);

    dim3 g3(cur / 128, 8);
    mfma_gemm<256, 1024, 0, 1><<<g3, 256, 0, stream>>>(h2, Wt3, b3, out, p0, NPTS);
  }
}